// Round 9
// baseline (59.124 us; speedup 1.0000x reference)
//
#include <hip/hip_runtime.h>
#include <stdint.h>

#define HW     16384
#define WDIM   128
#define CDIM   64
#define BDIM   32
#define ROWS   8
#define NBG    512      // fused blocks: (b, rowgroup of 8) -> exactly 2/CU
#define NBF    4096     // (b,row) partial rows
#define NBC    2048     // (b,c) pairs

// ws layout (bytes). Per-channel partials C-MAJOR [64][4096] for coalesced k3.
#define OFF_WMAX  0
#define OFF_WIDX  (1u << 20)
#define OFF_WSF   (2u << 20)
#define OFF_WS0   (3u << 20)
#define OFF_WSJ   (4u << 20)
#define OFF_WSQJ  (5u << 20)
#define OFF_WA1   (6u << 20)
#define OFF_WA2   ((6u << 20) + 32768u)
#define OFF_K3    ((6u << 20) + 65536u)

// async global->LDS, 16B per lane (fire-and-forget; can't be sunk by compiler)
__device__ __forceinline__ void dma16(const float* g, float* l) {
    __builtin_amdgcn_global_load_lds(
        (const __attribute__((address_space(1))) void*)g,
        (__attribute__((address_space(3))) void*)l, 16, 0, 0);
}

// raw barriers: do NOT drain vmcnt (keeps DMA in flight across phases)
#define BAR_LGKM() do { asm volatile("s_waitcnt lgkmcnt(0)" ::: "memory"); \
                        __builtin_amdgcn_s_barrier(); } while (0)
#define BAR_ALL()  do { asm volatile("s_waitcnt vmcnt(0) lgkmcnt(0)" ::: "memory"); \
                        __builtin_amdgcn_s_barrier(); } while (0)

// Single pass, DMA double-buffered. Block = (b, 8-row group).
// LDS tile quad-swizzled: logical (c, quad qx) stored at physical quad qx^(c&7)
// (applied on the GLOBAL source address; LDS dest stays linear for gload_lds).
// Bank behavior: 2a column reads 2-way (free); 2b b128 row reads optimal 8-cyc.
__global__ __launch_bounds__(256, 2) void f_fused(const float* __restrict__ feat,
                                                  float* __restrict__ wmax, int* __restrict__ widx,
                                                  float* __restrict__ wsf,  float* __restrict__ ws0,
                                                  float* __restrict__ wsj,  float* __restrict__ wsqj,
                                                  double* __restrict__ wa1, double* __restrict__ wa2) {
    __shared__ __align__(16) float tile[2][CDIM * 128];   // 2 x 32 KB
    __shared__ float scratch[1792];                        // 2a sc2[384] / 2b scb[1792]
    __shared__ float sred[4];

    const int t  = threadIdx.x;
    const int bq = blockIdx.x;               // b*16 + rowgroup
    const int b  = bq >> 4, rg = bq & 15;
    const int row0 = rg * ROWS;
    const float* base = feat + (size_t)b * CDIM * HW + (size_t)row0 * WDIM;

    // per-thread DMA geometry: slot idx = k*256+t -> c = idx>>5, qp = idx&31,
    // source quad qx = qp ^ (c&7)  (inverse swizzle on global side)
    int dma_c[8], dma_qx[8], dma_idx[8];
    #pragma unroll
    for (int k = 0; k < 8; ++k) {
        int idx = k * 256 + t;
        int c = idx >> 5, qp = idx & 31;
        dma_idx[k] = idx; dma_c[k] = c; dma_qx[k] = qp ^ (c & 7);
    }

    const int px = t & 127, half = t >> 7;                // 2a roles
    const int pq = px >> 2, pm = px & 3;
    const int ch = t & 63, sub = t >> 6, p0 = sub * 32;   // 2b roles

    // prologue: stage row 0 into buffer 0
    #pragma unroll
    for (int k = 0; k < 8; ++k)
        dma16(base + (size_t)dma_c[k] * HW + (dma_qx[k] << 2), &tile[0][dma_idx[k] * 4]);
    BAR_ALL();

    #pragma unroll
    for (int r = 0; r < ROWS; ++r) {
        const int cur = r & 1;
        const int bf = b * 128 + row0 + r;

        // issue NEXT row's DMA into the other buffer (in flight across processing)
        if (r < ROWS - 1) {
            const float* nb = base + (size_t)(r + 1) * WDIM;
            #pragma unroll
            for (int k = 0; k < 8; ++k)
                dma16(nb + (size_t)dma_c[k] * HW + (dma_qx[k] << 2), &tile[cur ^ 1][dma_idx[k] * 4]);
        }

        // ---- 2a scan: thread (px, half) scans 32 channels at fixed pixel
        float m1 = -INFINITY, m2 = -INFINITY, s2 = 0.f;
        #pragma unroll
        for (int cc = 0; cc < 32; ++cc) {
            int c = half * 32 + cc;
            float x = tile[cur][c * 128 + ((pq ^ (c & 7)) << 2) + pm];
            if (x > m1) { m2 = m1; m1 = x; } else { m2 = fmaxf(m2, x); }
            s2 = fmaf(x, x, s2);
        }
        if (half) { scratch[px * 3] = m1; scratch[px * 3 + 1] = m2; scratch[px * 3 + 2] = s2; }
        BAR_LGKM();   // B2

        // ---- 2b scan: thread (ch, sub) scans 32 px as 8 x float4 (swizzled quads)
        float bm = -INFINITY; int bi = 0;
        float sf = 0.f, s0 = 0.f, sjl = 0.f, sql = 0.f;
        #pragma unroll
        for (int qq = 0; qq < 8; ++qq) {
            int qx = (p0 >> 2) + qq;
            const float4 v = *reinterpret_cast<const float4*>(
                &tile[cur][ch * 128 + ((qx ^ (ch & 7)) << 2)]);
            float xs[4] = {v.x, v.y, v.z, v.w};
            #pragma unroll
            for (int e = 0; e < 4; ++e) {
                int i = qq * 4 + e;                  // compile-time
                float x = xs[e];
                if (x > bm) { bm = x; bi = i; }      // ascending i: first occurrence
                sf += x;
                float q = x * x;
                s0 += q;
                sjl = fmaf(q, (float)i, sjl);
                sql = fmaf(q, (float)(i * i), sql);
            }
        }

        // ---- 2a merge + shfl reduce (waves 0-1; wave-uniform branch)
        if (!half) {
            float n1 = scratch[px * 3], n2 = scratch[px * 3 + 1], s2b = scratch[px * 3 + 2];
            float mm1 = fmaxf(m1, n1);
            float mm2 = fmaxf(fminf(m1, n1), fmaxf(m2, n2));
            float S2 = s2 + s2b;
            float qq2 = mm1 * mm1, rr2 = S2 - qq2;
            float a1 = qq2 * rr2 + mm2 * mm2 * qq2;
            float a2 = mm1 * rr2 + mm2 * qq2;
            #pragma unroll
            for (int off = 32; off > 0; off >>= 1) {
                a1 += __shfl_down(a1, off);
                a2 += __shfl_down(a2, off);
            }
            if (t == 0)  { sred[0] = a1; sred[1] = a2; }
            if (t == 64) { sred[2] = a1; sred[3] = a2; }
        }
        BAR_LGKM();   // B3: scratch reusable, sred visible

        // ---- write 2b sub-partials
        {
            float sj  = fmaf((float)p0, s0, sjl);
            float sqj = fmaf((float)(p0 * p0), s0, fmaf(2.f * (float)p0, sjl, sql));
            int o = (sub * 64 + ch) * 7;
            scratch[o]     = bm;
            scratch[o + 1] = __int_as_float(p0 + bi);
            scratch[o + 2] = sf; scratch[o + 3] = s0;
            scratch[o + 4] = sj; scratch[o + 5] = sqj;
        }
        if (t == 255) {
            wa1[bf] = (double)(sred[0] + sred[2]);
            wa2[bf] = (double)(sred[1] + sred[3]);
        }
        BAR_LGKM();   // B4

        // ---- combine 4 subs per channel, write c-major partials
        if (t < 64) {
            float M = -INFINITY; int P = 0;
            float SF = 0.f, S0 = 0.f, SJ = 0.f, SQ = 0.f;
            #pragma unroll
            for (int s = 0; s < 4; ++s) {
                int oo = (s * 64 + t) * 7;
                float m = scratch[oo];
                if (m > M) { M = m; P = __float_as_int(scratch[oo + 1]); }
                SF += scratch[oo + 2]; S0 += scratch[oo + 3];
                SJ += scratch[oo + 4]; SQ += scratch[oo + 5];
            }
            int out = t * 4096 + bf;
            wmax[out] = M; widx[out] = P;
            wsf[out] = SF; ws0[out] = S0; wsj[out] = SJ; wsqj[out] = SQ;
        }

        // next tile ready + everyone done with cur (single vmcnt drain per row)
        BAR_ALL();
    }
}

// One block per (b,c): merge 128 row partials (unit-stride coalesced).
__global__ __launch_bounds__(128) void k3_channel(const float* __restrict__ wmax, const int* __restrict__ widx,
                                                  const float* __restrict__ wsf,  const float* __restrict__ ws0,
                                                  const float* __restrict__ wsj,  const float* __restrict__ wsqj,
                                                  double* __restrict__ k3out) {
    const int bc = blockIdx.x;
    const int b = bc >> 6, c = bc & 63;
    const int t = threadIdx.x;             // row
    const int idx = c * 4096 + b * 128 + t;

    float m = wmax[idx]; int px = widx[idx];
    float sf = wsf[idx], s0 = ws0[idx], sj = wsj[idx], sqj = wsqj[idx];

    __shared__ float rm[128]; __shared__ int rr[128]; __shared__ int rp[128];
    rm[t] = m; rr[t] = t; rp[t] = px;
    __syncthreads();
    for (int off = 64; off > 0; off >>= 1) {
        if (t < off) {
            float mo = rm[t + off];
            if (mo > rm[t] || (mo == rm[t] && rr[t + off] < rr[t])) {
                rm[t] = mo; rr[t] = rr[t + off]; rp[t] = rp[t + off];
            }
        }
        __syncthreads();
    }
    const int mi = rr[0], mj = rp[0];

    double di = (double)(mi - t);
    double disc = (di * di + (double)mj * (double)mj) * (double)s0
                - 2.0 * (double)mj * (double)sj + (double)sqj;

    __shared__ double rd[128], rsf[128], rs0[128];
    rd[t] = disc; rsf[t] = (double)sf; rs0[t] = (double)s0;
    __syncthreads();
    for (int off = 64; off > 0; off >>= 1) {
        if (t < off) { rd[t] += rd[t + off]; rsf[t] += rsf[t + off]; rs0[t] += rs0[t + off]; }
        __syncthreads();
    }
    if (t == 0) {
        k3out[bc * 3]     = rsf[0];
        k3out[bc * 3 + 1] = rs0[0];
        k3out[bc * 3 + 2] = rd[0];
    }
}

__global__ __launch_bounds__(256) void k4_final(const double* __restrict__ k3out,
                                                const double* __restrict__ wa1,
                                                const double* __restrict__ wa2,
                                                float* __restrict__ out) {
    const int t = threadIdx.x;
    double sf = 0, s0 = 0, dis = 0, a1 = 0, a2 = 0;
    for (int i = t; i < NBC; i += 256) {
        sf += k3out[i * 3]; s0 += k3out[i * 3 + 1]; dis += k3out[i * 3 + 2];
    }
    for (int i = t; i < NBF; i += 256) { a1 += wa1[i]; a2 += wa2[i]; }

    __shared__ double r[5][256];
    r[0][t] = sf; r[1][t] = s0; r[2][t] = dis; r[3][t] = a1; r[4][t] = a2;
    __syncthreads();
    for (int off = 128; off > 0; off >>= 1) {
        if (t < off) {
            #pragma unroll
            for (int q = 0; q < 5; ++q) r[q][t] += r[q][t + off];
        }
        __syncthreads();
    }
    if (t == 0) {
        const double n = 33554432.0; // 32*64*128*128
        double mgr = r[0][0] / n;
        out[0] = (float)(r[2][0] / n);
        out[1] = (float)((r[3][0] - 2.0 * mgr * r[4][0] + mgr * mgr * r[1][0]) / n);
    }
}

extern "C" void kernel_launch(void* const* d_in, const int* in_sizes, int n_in,
                              void* d_out, int out_size, void* d_ws, size_t ws_size,
                              hipStream_t stream) {
    const float* feat = (const float*)d_in[0];
    float* out = (float*)d_out;
    char* ws = (char*)d_ws;

    float*  wmax = (float*)(ws + OFF_WMAX);
    int*    widx = (int*)  (ws + OFF_WIDX);
    float*  wsf  = (float*)(ws + OFF_WSF);
    float*  ws0  = (float*)(ws + OFF_WS0);
    float*  wsj  = (float*)(ws + OFF_WSJ);
    float*  wsqj = (float*)(ws + OFF_WSQJ);
    double* wa1  = (double*)(ws + OFF_WA1);
    double* wa2  = (double*)(ws + OFF_WA2);
    double* k3o  = (double*)(ws + OFF_K3);

    f_fused<<<NBG, 256, 0, stream>>>(feat, wmax, widx, wsf, ws0, wsj, wsqj, wa1, wa2);
    k3_channel<<<NBC, 128, 0, stream>>>(wmax, widx, wsf, ws0, wsj, wsqj, k3o);
    k4_final<<<1, 256, 0, stream>>>(k3o, wa1, wa2, out);
}